// Round 4
// baseline (349.059 us; speedup 1.0000x reference)
//
#include <hip/hip_runtime.h>
#include <hip/hip_bf16.h>
#include <math.h>

constexpr int kBS = 2;
constexpr int kNQ = 20197;
constexpr int kNV = 20197;
constexpr int kM  = kBS * kNQ;   // 40394
constexpr int kMpad = 40448;     // 316*128, slack rows for global_load_lds A-tiles

__constant__ int cLH[4] = {100, 50, 25, 13};
__constant__ int cLW[4] = {152, 76, 38, 19};
__constant__ int cLS[4] = {0, 15200, 19000, 19950};

typedef __bf16 bf16x8 __attribute__((ext_vector_type(8)));
typedef float  f32x4  __attribute__((ext_vector_type(4)));
typedef float  v2f    __attribute__((ext_vector_type(2)));

__device__ __forceinline__ unsigned short f2bf(float x) {
    unsigned u = __float_as_uint(x);
    return (unsigned short)((u + 0x7fffu + ((u >> 16) & 1u)) >> 16);
}
__device__ __forceinline__ unsigned pack2(float a, float b) {
    return (unsigned)f2bf(a) | ((unsigned)f2bf(b) << 16);
}
__device__ __forceinline__ float bflo(unsigned u) { return __uint_as_float(u << 16); }
__device__ __forceinline__ float bfhi(unsigned u) { return __uint_as_float(u & 0xffff0000u); }
__device__ __forceinline__ void gload_lds16(const void* g, void* s) {
    __builtin_amdgcn_global_load_lds(
        (const __attribute__((address_space(1))) void*)g,
        (__attribute__((address_space(3))) void*)s, 16, 0, 0);
}

// ---------------------------------------------------------------------------
// prep_all: value/query fp32 -> bf16 (vectorized 8/thread), weight transposes
// (fp32 KxN -> bf16 NxK), fused bias384. One launch, grid-stride.
// ---------------------------------------------------------------------------
__global__ __launch_bounds__(256) void prep_all(
    const float* __restrict__ value, const float* __restrict__ query,
    const float* __restrict__ Wv, const float* __restrict__ Wso,
    const float* __restrict__ Waw, const float* __restrict__ Wo,
    const float* __restrict__ bso, const float* __restrict__ baw,
    unsigned short* __restrict__ value_b, unsigned short* __restrict__ query_b,
    unsigned short* __restrict__ WvT, unsigned short* __restrict__ WsoawT,
    unsigned short* __restrict__ WoT, float* __restrict__ bias384)
{
    constexpr int NC = kM * 256 / 8;            // uint4 chunks per tensor
    constexpr int NW = 65536 + 98304 + 65536 + 384;
    const int stride = gridDim.x * 256;
    for (int i = blockIdx.x * 256 + threadIdx.x; i < 2 * NC + NW; i += stride) {
        if (i < 2 * NC) {
            const bool isv = i < NC;
            const int j = isv ? i : i - NC;
            const float4* src = (const float4*)(isv ? value : query);
            float4 f0 = src[2 * j], f1 = src[2 * j + 1];
            uint4 q = make_uint4(pack2(f0.x, f0.y), pack2(f0.z, f0.w),
                                 pack2(f1.x, f1.y), pack2(f1.z, f1.w));
            ((uint4*)(isv ? value_b : query_b))[j] = q;
        } else {
            int k = i - 2 * NC;
            if (k < 65536) { WvT[k] = f2bf(Wv[(k & 255) * 256 + (k >> 8)]); continue; }
            k -= 65536;
            if (k < 98304) {
                int n = k >> 8, kk = k & 255;
                WsoawT[k] = f2bf(n < 256 ? Wso[kk * 256 + n] : Waw[kk * 128 + (n - 256)]);
                continue;
            }
            k -= 98304;
            if (k < 65536) { WoT[k] = f2bf(Wo[(k & 255) * 256 + (k >> 8)]); continue; }
            k -= 65536;
            bias384[k] = (k < 256) ? bso[k] : baw[k - 256];
        }
    }
}

// ---------------------------------------------------------------------------
// Dual bf16 MFMA GEMM (one dispatch):
//   bx<2 : v_b[M,256]  = value_b @ WvT^T + bv      (bf16 out)
//   bx>=2: soaw[M,384] = query_b @ WsoawT^T + b384 (bf16 out)
// 128x128 tile, 256 thr (2x2 waves), BK=32, mfma 16x16x32, pure
// global_load_lds staging (m97 structure). A buffers have kMpad slack rows.
// ---------------------------------------------------------------------------
__global__ __launch_bounds__(256) void gemm_dual(
    const __hip_bfloat16* __restrict__ A0, const __hip_bfloat16* __restrict__ BT0,
    const float* __restrict__ bias0, unsigned short* __restrict__ C0,
    const __hip_bfloat16* __restrict__ A1, const __hip_bfloat16* __restrict__ BT1,
    const float* __restrict__ bias1, unsigned short* __restrict__ C1)
{
    __shared__ __hip_bfloat16 As[128 * 32];
    __shared__ __hip_bfloat16 Bs[128 * 32];

    const int bx = blockIdx.x;
    const bool second = bx >= 2;
    const __hip_bfloat16* A  = second ? A1 : A0;
    const __hip_bfloat16* BT = second ? BT1 : BT0;
    const float* bias = second ? bias1 : bias0;
    unsigned short* C = second ? C1 : C0;
    const int N  = second ? 384 : 256;
    const int n0 = (second ? bx - 2 : bx) * 128;
    const int m0 = blockIdx.y * 128;

    const int t = threadIdx.x;
    const int wave = t >> 6, lane = t & 63;
    const int quad = lane >> 4, l16 = lane & 15;
    const int mw = (wave & 1) * 64, nw = (wave >> 1) * 64;

    f32x4 acc[4][4] = {};

    for (int k0 = 0; k0 < 256; k0 += 32) {
        __syncthreads();
        const char* bt = (const char*)BT;
        const char* ab = (const char*)A;
        #pragma unroll
        for (int j = 0; j < 2; ++j) {
            int off = j * 4096 + t * 16;
            int row = off >> 6, kb = off & 63;
            gload_lds16(bt + (size_t)(n0 + row) * 512 + k0 * 2 + kb, (char*)Bs + off);
            gload_lds16(ab + (size_t)(m0 + row) * 512 + k0 * 2 + kb, (char*)As + off);
        }
        __syncthreads();
        bf16x8 afr[4], bfr[4];
        #pragma unroll
        for (int mt = 0; mt < 4; ++mt)
            afr[mt] = *(const bf16x8*)(const void*)&As[(mw + mt * 16 + l16) * 32 + quad * 8];
        #pragma unroll
        for (int nt = 0; nt < 4; ++nt)
            bfr[nt] = *(const bf16x8*)(const void*)&Bs[(nw + nt * 16 + l16) * 32 + quad * 8];
        #pragma unroll
        for (int mt = 0; mt < 4; ++mt)
            #pragma unroll
            for (int nt = 0; nt < 4; ++nt)
                acc[mt][nt] = __builtin_amdgcn_mfma_f32_16x16x32_bf16(
                    afr[mt], bfr[nt], acc[mt][nt], 0, 0, 0);
    }

    #pragma unroll
    for (int nt = 0; nt < 4; ++nt) {
        int col = n0 + nw + nt * 16 + l16;
        float bvv = bias[col];
        #pragma unroll
        for (int mt = 0; mt < 4; ++mt) {
            #pragma unroll
            for (int i = 0; i < 4; ++i) {
                int row = m0 + mw + mt * 16 + quad * 4 + i;
                if (row < kM)
                    C[(size_t)row * N + col] = f2bf(acc[mt][nt][i] + bvv);
            }
        }
    }
}

// ---------------------------------------------------------------------------
// Final GEMM: out[M,256] = mid_b(bf16) @ WoT^T + bo + query (fp32 out)
// ---------------------------------------------------------------------------
__global__ __launch_bounds__(256) void gemm_final(
    const __hip_bfloat16* __restrict__ Ab, const __hip_bfloat16* __restrict__ BT,
    const float* __restrict__ bias, const float* __restrict__ res,
    float* __restrict__ C)
{
    __shared__ __hip_bfloat16 As[128 * 32];
    __shared__ __hip_bfloat16 Bs[128 * 32];

    const int t = threadIdx.x;
    const int wave = t >> 6, lane = t & 63;
    const int quad = lane >> 4, l16 = lane & 15;
    const int mw = (wave & 1) * 64, nw = (wave >> 1) * 64;
    const int m0 = blockIdx.y * 128, n0 = blockIdx.x * 128;

    f32x4 acc[4][4] = {};

    for (int k0 = 0; k0 < 256; k0 += 32) {
        __syncthreads();
        const char* bt = (const char*)BT;
        const char* ab = (const char*)Ab;
        #pragma unroll
        for (int j = 0; j < 2; ++j) {
            int off = j * 4096 + t * 16;
            int row = off >> 6, kb = off & 63;
            gload_lds16(bt + (size_t)(n0 + row) * 512 + k0 * 2 + kb, (char*)Bs + off);
            gload_lds16(ab + (size_t)(m0 + row) * 512 + k0 * 2 + kb, (char*)As + off);
        }
        __syncthreads();
        bf16x8 afr[4], bfr[4];
        #pragma unroll
        for (int mt = 0; mt < 4; ++mt)
            afr[mt] = *(const bf16x8*)(const void*)&As[(mw + mt * 16 + l16) * 32 + quad * 8];
        #pragma unroll
        for (int nt = 0; nt < 4; ++nt)
            bfr[nt] = *(const bf16x8*)(const void*)&Bs[(nw + nt * 16 + l16) * 32 + quad * 8];
        #pragma unroll
        for (int mt = 0; mt < 4; ++mt)
            #pragma unroll
            for (int nt = 0; nt < 4; ++nt)
                acc[mt][nt] = __builtin_amdgcn_mfma_f32_16x16x32_bf16(
                    afr[mt], bfr[nt], acc[mt][nt], 0, 0, 0);
    }

    #pragma unroll
    for (int nt = 0; nt < 4; ++nt) {
        int col = n0 + nw + nt * 16 + l16;
        float bvv = bias[col];
        #pragma unroll
        for (int mt = 0; mt < 4; ++mt) {
            #pragma unroll
            for (int i = 0; i < 4; ++i) {
                int row = m0 + mw + mt * 16 + quad * 4 + i;
                if (row < kM)
                    C[(size_t)row * 256 + col] =
                        acc[mt][nt][i] + bvv + res[(size_t)row * 256 + col];
            }
        }
    }
}

// ---------------------------------------------------------------------------
// Sampler: 256 threads = 2 queries, 4 waves; 2 waves per query (8 points
// each, dwordx2 gathers, 4 channels/lane) -> 80.8k waves total for MLP.
// Phase 1: 256 threads <-> 256 (q,h,l,p) points (softmax + geometry -> LDS,
// stride-17 slots for conflict-free b128 phase-2 reads).
// Phase 2: gather + packed FMA; partials combined through LDS.
// ---------------------------------------------------------------------------
__global__ __launch_bounds__(256) void msda_sample(
    const __hip_bfloat16* __restrict__ v,     // (BS*NV, 256) bf16
    const __hip_bfloat16* __restrict__ soaw,  // (M, 384) bf16: so | logits
    const float* __restrict__ rp,             // (M, 4, 2)
    __hip_bfloat16* __restrict__ mid)         // (kMpad, 256) bf16
{
    __shared__ int4   sOff[2 * 136];
    __shared__ float4 sW[2 * 136];
    __shared__ float4 sRed[128];
    const int t = threadIdx.x;

    {   // phase 1
        const int q = t >> 7, r = t & 127;
        const int h = r >> 4, lp = r & 15, l = lp >> 2;
        const int bq = blockIdx.x * 2 + q;
        unsigned sopk = *(const unsigned*)(const void*)(soaw + (size_t)bq * 384 + 2 * r);
        float logit = bflo((unsigned)*(const unsigned short*)(const void*)
                           (soaw + (size_t)bq * 384 + 256 + r));
        float2 rr = *(const float2*)(rp + (size_t)bq * 8 + l * 2);
        float sx = bflo(sopk), sy = bfhi(sopk);

        float mx = logit;
        #pragma unroll
        for (int s = 8; s >= 1; s >>= 1) mx = fmaxf(mx, __shfl_xor(mx, s, 16));
        float e = __expf(logit - mx);
        float sum = e;
        #pragma unroll
        for (int s = 8; s >= 1; s >>= 1) sum += __shfl_xor(sum, s, 16);
        float w = e / sum;

        const int ww = cLW[l], hh = cLH[l];
        const float fw = (float)ww, fh = (float)hh;
        float x = rr.x * fw + sx - 0.5f;   // == (rx + so/w)*w - 0.5
        float y = rr.y * fh + sy - 0.5f;
        float xf = floorf(x), yf = floorf(y);
        int x0 = (int)xf, y0 = (int)yf;
        float wx1 = x - xf, wx0 = 1.f - wx1;
        float wy1 = y - yf, wy0 = 1.f - wy1;
        bool vx0 = (x0 >= 0) & (x0 < ww);
        bool vx1 = (x0 >= -1) & (x0 + 1 < ww);
        bool vy0 = (y0 >= 0) & (y0 < hh);
        bool vy1 = (y0 >= -1) & (y0 + 1 < hh);
        int cx0 = min(max(x0, 0), ww - 1);
        int cx1 = min(max(x0 + 1, 0), ww - 1);
        int cy0 = min(max(y0, 0), hh - 1);
        int cy1 = min(max(y0 + 1, 0), hh - 1);
        const int base = cLS[l] * 256 + h * 32;

        const int slot = q * 136 + h * 17 + lp;
        sOff[slot] = make_int4(base + (cy0 * ww + cx0) * 256,
                               base + (cy0 * ww + cx1) * 256,
                               base + (cy1 * ww + cx0) * 256,
                               base + (cy1 * ww + cx1) * 256);
        sW[slot] = make_float4((vx0 & vy0) ? w * wx0 * wy0 : 0.f,
                               (vx1 & vy0) ? w * wx1 * wy0 : 0.f,
                               (vx0 & vy1) ? w * wx0 * wy1 : 0.f,
                               (vx1 & vy1) ? w * wx1 * wy1 : 0.f);
    }
    __syncthreads();

    // phase 2: wave w: q = w>>1, half = w&1 (points half*8 .. +8)
    const int wave = t >> 6, q = wave >> 1, half = wave & 1;
    const int h = (t >> 3) & 7, c = (t & 7) * 4;
    const int bq = blockIdx.x * 2 + q;
    const int b = (bq >= kNQ) ? 1 : 0;
    const __hip_bfloat16* vb = v + (size_t)b * kNV * 256 + c;

    v2f acc01 = {0.f, 0.f}, acc23 = {0.f, 0.f};
    #pragma unroll 4
    for (int pp = 0; pp < 8; ++pp) {
        const int slot = q * 136 + h * 17 + half * 8 + pp;
        int4   o  = sOff[slot];
        float4 wv = sW[slot];
        {
            uint2 u = *(const uint2*)(const void*)(vb + o.x);
            v2f lo = {bflo(u.x), bfhi(u.x)}, hi = {bflo(u.y), bfhi(u.y)};
            acc01 += wv.x * lo; acc23 += wv.x * hi;
        }
        {
            uint2 u = *(const uint2*)(const void*)(vb + o.y);
            v2f lo = {bflo(u.x), bfhi(u.x)}, hi = {bflo(u.y), bfhi(u.y)};
            acc01 += wv.y * lo; acc23 += wv.y * hi;
        }
        {
            uint2 u = *(const uint2*)(const void*)(vb + o.z);
            v2f lo = {bflo(u.x), bfhi(u.x)}, hi = {bflo(u.y), bfhi(u.y)};
            acc01 += wv.z * lo; acc23 += wv.z * hi;
        }
        {
            uint2 u = *(const uint2*)(const void*)(vb + o.w);
            v2f lo = {bflo(u.x), bfhi(u.x)}, hi = {bflo(u.y), bfhi(u.y)};
            acc01 += wv.w * lo; acc23 += wv.w * hi;
        }
    }

    if (half)
        sRed[q * 64 + (t & 63)] = make_float4(acc01.x, acc01.y, acc23.x, acc23.y);
    __syncthreads();
    if (!half) {
        float4 o = sRed[q * 64 + (t & 63)];
        uint2 pk = make_uint2(pack2(acc01.x + o.x, acc01.y + o.y),
                              pack2(acc23.x + o.z, acc23.y + o.w));
        *(uint2*)(void*)(mid + (size_t)bq * 256 + h * 32 + c) = pk;
    }
}

// ---------------------------------------------------------------------------
extern "C" void kernel_launch(void* const* d_in, const int* in_sizes, int n_in,
                              void* d_out, int out_size, void* d_ws, size_t ws_size,
                              hipStream_t stream)
{
    const float* query = (const float*)d_in[0];
    const float* value = (const float*)d_in[1];
    const float* rp    = (const float*)d_in[2];
    const float* Wv  = (const float*)d_in[5];
    const float* bv  = (const float*)d_in[6];
    const float* Wso = (const float*)d_in[7];
    const float* bso = (const float*)d_in[8];
    const float* Waw = (const float*)d_in[9];
    const float* baw = (const float*)d_in[10];
    const float* Wo  = (const float*)d_in[11];
    const float* bo  = (const float*)d_in[12];

    // d_out overlay: value_b (kMpad rows, slack rows benignly overlap v_b
    // start -- slack reads are masked at the MFMA epilogue) | v_b.
    // Final GEMM rewrites all of d_out.
    unsigned short* value_b = (unsigned short*)d_out;
    __hip_bfloat16* v_b     = (__hip_bfloat16*)((char*)d_out + (size_t)kM * 512);

    // ws: soaw bf16 (kM*384) | query_b/mid_b aliased (kMpad*256 bf16, query_b
    // dead before sampler writes mid_b) | WvT | WsoawT | WoT | bias384
    char* p = (char*)d_ws;
    __hip_bfloat16* soaw = (__hip_bfloat16*)p;   p += (size_t)kM * 384 * 2;
    unsigned short* query_b = (unsigned short*)p;
    __hip_bfloat16* mid_b   = (__hip_bfloat16*)p; p += (size_t)kMpad * 256 * 2;
    unsigned short* WvT    = (unsigned short*)p; p += 256 * 256 * 2;
    unsigned short* WsoawT = (unsigned short*)p; p += 384 * 256 * 2;
    unsigned short* WoT    = (unsigned short*)p; p += 256 * 256 * 2;
    float* bias384         = (float*)p;

    hipLaunchKernelGGL(prep_all, dim3(2048), dim3(256), 0, stream,
                       value, query, Wv, Wso, Waw, Wo, bso, baw,
                       value_b, query_b, WvT, WsoawT, WoT, bias384);

    hipLaunchKernelGGL(gemm_dual, dim3(5, 316), dim3(256), 0, stream,
                       (const __hip_bfloat16*)value_b, (const __hip_bfloat16*)WvT,
                       bv, (unsigned short*)v_b,
                       (const __hip_bfloat16*)query_b, (const __hip_bfloat16*)WsoawT,
                       bias384, (unsigned short*)soaw);

    hipLaunchKernelGGL(msda_sample, dim3(kM / 2), dim3(256), 0, stream,
                       v_b, soaw, rp, mid_b);

    hipLaunchKernelGGL(gemm_final, dim3(2, 316), dim3(256), 0, stream,
                       mid_b, (const __hip_bfloat16*)WoT, bo, query, (float*)d_out);
}

// Round 6
// 299.598 us; speedup vs baseline: 1.1651x; 1.1651x over previous
//
#include <hip/hip_runtime.h>
#include <hip/hip_bf16.h>
#include <math.h>

constexpr int kBS = 2;
constexpr int kNQ = 20197;
constexpr int kNV = 20197;
constexpr int kM  = kBS * kNQ;   // 40394
constexpr int kMT = 632;         // 64-row m-tiles (40448 rows incl. slack)
constexpr int kMpad = kMT * 64;  // 40448

__constant__ int cLH[4] = {100, 50, 25, 13};
__constant__ int cLW[4] = {152, 76, 38, 19};
__constant__ int cLS[4] = {0, 15200, 19000, 19950};

typedef __bf16 bf16x8 __attribute__((ext_vector_type(8)));
typedef float  f32x4  __attribute__((ext_vector_type(4)));

__device__ __forceinline__ unsigned short f2bf(float x) {
    unsigned u = __float_as_uint(x);
    return (unsigned short)((u + 0x7fffu + ((u >> 16) & 1u)) >> 16);
}
__device__ __forceinline__ unsigned pack2(float a, float b) {
    return (unsigned)f2bf(a) | ((unsigned)f2bf(b) << 16);
}
__device__ __forceinline__ float bflo(unsigned u) { return __uint_as_float(u << 16); }
__device__ __forceinline__ float bfhi(unsigned u) { return __uint_as_float(u & 0xffff0000u); }
__device__ __forceinline__ void gload_lds16(const void* g, void* s) {
    __builtin_amdgcn_global_load_lds(
        (const __attribute__((address_space(1))) void*)g,
        (__attribute__((address_space(3))) void*)s, 16, 0, 0);
}

// ---------------------------------------------------------------------------
// prep_w: weight transposes only (fp32 KxN -> bf16 NxK) + fused bias384.
// ---------------------------------------------------------------------------
__global__ __launch_bounds__(256) void prep_w(
    const float* __restrict__ Wv, const float* __restrict__ Wso,
    const float* __restrict__ Waw, const float* __restrict__ Wo,
    const float* __restrict__ bso, const float* __restrict__ baw,
    unsigned short* __restrict__ WvT, unsigned short* __restrict__ WsoawT,
    unsigned short* __restrict__ WoT, float* __restrict__ bias384)
{
    int k = blockIdx.x * 256 + threadIdx.x;
    if (k < 65536) { WvT[k] = f2bf(Wv[(k & 255) * 256 + (k >> 8)]); return; }
    k -= 65536;
    if (k < 98304) {
        int n = k >> 8, kk = k & 255;
        WsoawT[k] = f2bf(n < 256 ? Wso[kk * 256 + n] : Waw[kk * 128 + (n - 256)]);
        return;
    }
    k -= 98304;
    if (k < 65536) { WoT[k] = f2bf(Wo[(k & 255) * 256 + (k >> 8)]); return; }
    k -= 65536;
    if (k < 384) bias384[k] = (k < 256) ? bso[k] : baw[k - 256];
}

// ---------------------------------------------------------------------------
// Panel GEMM core: C[64, N] = A_tile[64, 256] @ BT[N, 256]^T + bias (+res).
// A tile staged into LDS ONCE (pitch 264), then loop over n-tiles with
// double-buffered B panels via global_load_lds. 256 thr, 4 waves (2x2 over
// 32x64 outputs each), mfma 16x16x32, acc 2x4.
// ---------------------------------------------------------------------------
template<int AFP32, int CFP32>
__device__ __forceinline__ void gemm_core(
    const void* __restrict__ Av, const __hip_bfloat16* __restrict__ BT,
    const float* __restrict__ bias, const float* __restrict__ res,
    int N, int NT, void* __restrict__ Cv, int m0)
{
    __shared__ __hip_bfloat16 As[64 * 264];
    __shared__ __hip_bfloat16 Bs[2][128 * 32];

    const int t = threadIdx.x;
    const int wave = t >> 6, lane = t & 63;
    const int quad = lane >> 4, l16 = lane & 15;
    const int mw = (wave & 1) * 32, nw = (wave >> 1) * 64;

    auto issueB = [&](int nti, int kc, int buf) {
        #pragma unroll
        for (int j = 0; j < 2; ++j) {
            int off = j * 4096 + t * 16;
            int row = off >> 6, kb = off & 63;
            gload_lds16((const char*)BT + (size_t)(nti * 128 + row) * 512 + kc * 64 + kb,
                        (char*)&Bs[buf][0] + off);
        }
    };

    issueB(0, 0, 0);   // first B panel in flight during A staging

    if (AFP32) {
        const float* af = (const float*)Av;
        #pragma unroll
        for (int p = 0; p < 16; ++p) {
            int idx = p * 256 + t;
            int row = idx >> 6, col4 = idx & 63;
            float4 f = make_float4(0.f, 0.f, 0.f, 0.f);
            if (m0 + row < kM)
                f = *(const float4*)(af + (size_t)(m0 + row) * 256 + col4 * 4);
            uint2 u = make_uint2(pack2(f.x, f.y), pack2(f.z, f.w));
            *(uint2*)(void*)&As[row * 264 + col4 * 4] = u;
        }
    } else {
        const unsigned short* ab = (const unsigned short*)Av;  // kMpad rows: no guard
        #pragma unroll
        for (int p = 0; p < 8; ++p) {          // BUGFIX: was p < 4 (rows 32-63 unstaged)
            int idx = p * 256 + t;
            int row = idx >> 5, ch = idx & 31;
            uint4 u = *(const uint4*)(ab + (size_t)(m0 + row) * 256 + ch * 8);
            *(uint4*)(void*)&As[row * 264 + ch * 8] = u;
        }
    }

    for (int nti = 0; nti < NT; ++nti) {
        f32x4 acc[2][4] = {};
        for (int kc = 0; kc < 8; ++kc) {
            __syncthreads();     // drains current B panel (+ A stage on iter 0)
            if (kc < 7)             issueB(nti, kc + 1, (kc + 1) & 1);
            else if (nti + 1 < NT)  issueB(nti + 1, 0, 0);
            bf16x8 afr[2], bfr[4];
            #pragma unroll
            for (int mt = 0; mt < 2; ++mt)
                afr[mt] = *(const bf16x8*)(const void*)
                    &As[(mw + mt * 16 + l16) * 264 + kc * 32 + quad * 8];
            #pragma unroll
            for (int nt = 0; nt < 4; ++nt)
                bfr[nt] = *(const bf16x8*)(const void*)
                    &Bs[kc & 1][(nw + nt * 16 + l16) * 32 + quad * 8];
            #pragma unroll
            for (int mt = 0; mt < 2; ++mt)
                #pragma unroll
                for (int nt = 0; nt < 4; ++nt)
                    acc[mt][nt] = __builtin_amdgcn_mfma_f32_16x16x32_bf16(
                        afr[mt], bfr[nt], acc[mt][nt], 0, 0, 0);
        }
        // epilogue for this n-tile (C/D: col=lane&15, row=quad*4+reg)
        const int n0g = nti * 128;
        #pragma unroll
        for (int nt = 0; nt < 4; ++nt) {
            int col = n0g + nw + nt * 16 + l16;
            float bvv = bias[col];
            #pragma unroll
            for (int mt = 0; mt < 2; ++mt) {
                #pragma unroll
                for (int i = 0; i < 4; ++i) {
                    int row = m0 + mw + mt * 16 + quad * 4 + i;
                    if (row < kM) {
                        float val = acc[mt][nt][i] + bvv;
                        if (CFP32)
                            ((float*)Cv)[(size_t)row * N + col] =
                                val + res[(size_t)row * N + col];
                        else
                            ((unsigned short*)Cv)[(size_t)row * N + col] = f2bf(val);
                    }
                }
            }
        }
    }
}

// bx=0: v_b = value @ WvT^T + bv; bx=1: soaw = query @ WsoawT^T + bias384
__global__ __launch_bounds__(256, 3) void gemm_dual(
    const float* __restrict__ value, const __hip_bfloat16* __restrict__ WvT,
    const float* __restrict__ bv, unsigned short* __restrict__ v_b,
    const float* __restrict__ query, const __hip_bfloat16* __restrict__ WsoawT,
    const float* __restrict__ b384, unsigned short* __restrict__ soaw)
{
    const int m0 = blockIdx.y * 64;
    const float* A; const __hip_bfloat16* BT; const float* bias;
    unsigned short* C; int N, NT;
    if (blockIdx.x == 0) { A = value; BT = WvT;    bias = bv;   C = v_b;  N = 256; NT = 2; }
    else                 { A = query; BT = WsoawT; bias = b384; C = soaw; N = 384; NT = 3; }
    gemm_core<1, 0>(A, BT, bias, nullptr, N, NT, C, m0);
}

// out = mid_b(bf16) @ WoT^T + bo + query (fp32 out)
__global__ __launch_bounds__(256, 3) void gemm_final(
    const unsigned short* __restrict__ mid_b, const __hip_bfloat16* __restrict__ WoT,
    const float* __restrict__ bo, const float* __restrict__ query,
    float* __restrict__ out)
{
    gemm_core<0, 1>(mid_b, WoT, bo, query, 256, 2, out, blockIdx.y * 64);
}

// ---------------------------------------------------------------------------
// Sampler: EXACT R2 structure (96 us proven): 1 block (128 thr) per query.
// ---------------------------------------------------------------------------
__global__ __launch_bounds__(128) void msda_sample(
    const __hip_bfloat16* __restrict__ v,     // (BS*NV, 256) bf16
    const __hip_bfloat16* __restrict__ soaw,  // (M, 384) bf16: so | logits
    const float* __restrict__ rp,             // (M, 4, 2)
    __hip_bfloat16* __restrict__ mid)         // (kMpad, 256) bf16
{
    const int bq = blockIdx.x;
    const int b  = bq >= kNQ;
    const int t  = threadIdx.x;

    __shared__ int   sOff[128 * 5];
    __shared__ float sW[128 * 5];

    {   // phase 1
        const int h = t >> 4, lp = t & 15, l = lp >> 2;
        unsigned sopk = *(const unsigned*)(const void*)(soaw + (size_t)bq * 384 + 2 * t);
        float logit = bflo((unsigned)*(const unsigned short*)(const void*)
                           (soaw + (size_t)bq * 384 + 256 + t));
        float2 rr = *(const float2*)(rp + (size_t)bq * 8 + l * 2);
        float sx = bflo(sopk), sy = bfhi(sopk);

        float mx = logit;
        #pragma unroll
        for (int s = 8; s >= 1; s >>= 1) mx = fmaxf(mx, __shfl_xor(mx, s, 16));
        float e = __expf(logit - mx);
        float sum = e;
        #pragma unroll
        for (int s = 8; s >= 1; s >>= 1) sum += __shfl_xor(sum, s, 16);
        float w = e / sum;

        const int ww = cLW[l], hh = cLH[l];
        const float fw = (float)ww, fh = (float)hh;
        float x = rr.x * fw + sx - 0.5f;   // == (rx + so/w)*w - 0.5
        float y = rr.y * fh + sy - 0.5f;
        float xf = floorf(x), yf = floorf(y);
        int x0 = (int)xf, y0 = (int)yf;
        float wx1 = x - xf, wx0 = 1.f - wx1;
        float wy1 = y - yf, wy0 = 1.f - wy1;
        bool vx0 = (x0 >= 0) & (x0 < ww);
        bool vx1 = (x0 >= -1) & (x0 + 1 < ww);
        bool vy0 = (y0 >= 0) & (y0 < hh);
        bool vy1 = (y0 >= -1) & (y0 + 1 < hh);
        int cx0 = min(max(x0, 0), ww - 1);
        int cx1 = min(max(x0 + 1, 0), ww - 1);
        int cy0 = min(max(y0, 0), hh - 1);
        int cy1 = min(max(y0 + 1, 0), hh - 1);
        const int base = cLS[l] * 256 + h * 32;
        sOff[t * 5 + 0] = base + (cy0 * ww + cx0) * 256;
        sOff[t * 5 + 1] = base + (cy0 * ww + cx1) * 256;
        sOff[t * 5 + 2] = base + (cy1 * ww + cx0) * 256;
        sOff[t * 5 + 3] = base + (cy1 * ww + cx1) * 256;
        sW[t * 5 + 0] = (vx0 & vy0) ? w * wx0 * wy0 : 0.f;
        sW[t * 5 + 1] = (vx1 & vy0) ? w * wx1 * wy0 : 0.f;
        sW[t * 5 + 2] = (vx0 & vy1) ? w * wx0 * wy1 : 0.f;
        sW[t * 5 + 3] = (vx1 & vy1) ? w * wx1 * wy1 : 0.f;
    }
    __syncthreads();

    // phase 2
    const int h = t >> 4, c = (t & 15) * 2;
    const __hip_bfloat16* vb = v + (size_t)b * kNV * 256 + c;
    float accx = 0.f, accy = 0.f;
    const int p0 = h * 16;
    #pragma unroll 4
    for (int pp = 0; pp < 16; ++pp) {
        const int idx = (p0 + pp) * 5;
        #pragma unroll
        for (int k2 = 0; k2 < 4; ++k2) {
            float wgt = sW[idx + k2];
            int   off = sOff[idx + k2];
            unsigned u = *(const unsigned*)(const void*)(vb + off);
            accx += wgt * bflo(u);
            accy += wgt * bfhi(u);
        }
    }
    *(unsigned*)(void*)(mid + (size_t)bq * 256 + h * 32 + c) = pack2(accx, accy);
}

// ---------------------------------------------------------------------------
extern "C" void kernel_launch(void* const* d_in, const int* in_sizes, int n_in,
                              void* d_out, int out_size, void* d_ws, size_t ws_size,
                              hipStream_t stream)
{
    const float* query = (const float*)d_in[0];
    const float* value = (const float*)d_in[1];
    const float* rp    = (const float*)d_in[2];
    const float* Wv  = (const float*)d_in[5];
    const float* bv  = (const float*)d_in[6];
    const float* Wso = (const float*)d_in[7];
    const float* bso = (const float*)d_in[8];
    const float* Waw = (const float*)d_in[9];
    const float* baw = (const float*)d_in[10];
    const float* Wo  = (const float*)d_in[11];
    const float* bo  = (const float*)d_in[12];

    // d_out overlay: v_b bf16 (kM*512 B) in first half; dead before the
    // final GEMM rewrites all of d_out.
    unsigned short* v_b = (unsigned short*)d_out;

    // ws: soaw bf16 (kM*384) | mid_b bf16 (kMpad*256, slack rows read by
    // final-GEMM staging, masked at epilogue) | WvT | WsoawT | WoT | bias384
    char* p = (char*)d_ws;
    __hip_bfloat16* soaw  = (__hip_bfloat16*)p;  p += (size_t)kM * 384 * 2;
    unsigned short* mid_b = (unsigned short*)p;  p += (size_t)kMpad * 256 * 2;
    unsigned short* WvT    = (unsigned short*)p; p += 256 * 256 * 2;
    unsigned short* WsoawT = (unsigned short*)p; p += 384 * 256 * 2;
    unsigned short* WoT    = (unsigned short*)p; p += 256 * 256 * 2;
    float* bias384         = (float*)p;

    hipLaunchKernelGGL(prep_w, dim3(898), dim3(256), 0, stream,
                       Wv, Wso, Waw, Wo, bso, baw, WvT, WsoawT, WoT, bias384);

    hipLaunchKernelGGL(gemm_dual, dim3(2, kMT), dim3(256), 0, stream,
                       value, (const __hip_bfloat16*)WvT, bv, v_b,
                       query, (const __hip_bfloat16*)WsoawT, bias384,
                       (unsigned short*)soaw);

    hipLaunchKernelGGL(msda_sample, dim3(kM), dim3(128), 0, stream,
                       (const __hip_bfloat16*)v_b, soaw, rp, (__hip_bfloat16*)mid_b);

    hipLaunchKernelGGL(gemm_final, dim3(1, kMT), dim3(256), 0, stream,
                       mid_b, (const __hip_bfloat16*)WoT, bo, query, (float*)d_out);
}